// Round 8
// baseline (682.883 us; speedup 1.0000x reference)
//
#include <hip/hip_runtime.h>
#include <hip/hip_bf16.h>
#include <math.h>

typedef __attribute__((ext_vector_type(8))) __bf16 bf16x8;
typedef __attribute__((ext_vector_type(4))) float f32x4;

static __device__ __forceinline__ unsigned short f2bf(float f) {
    unsigned int u = __float_as_uint(f);
    u += 0x7fffu + ((u >> 16) & 1u);   // round-to-nearest-even
    return (unsigned short)(u >> 16);
}

// ---------------------------------------------------------------------------
// K1: row softmax of E -> W in bf16.  One block (256 thr) per row, N=2048.
// ---------------------------------------------------------------------------
__global__ void __launch_bounds__(256) softmax_rows_k(const float* __restrict__ E,
                                                      unsigned short* __restrict__ W,
                                                      int N) {
    __shared__ float red[4];
    const int t = threadIdx.x;
    const int lane = t & 63;
    const int w = t >> 6;
    const size_t row = blockIdx.x;
    const float* e = E + row * (size_t)N;

    float v[8];
    float mx = -3.402823466e38f;
#pragma unroll
    for (int i = 0; i < 8; ++i) { v[i] = e[t + (i << 8)]; mx = fmaxf(mx, v[i]); }
#pragma unroll
    for (int off = 32; off; off >>= 1) mx = fmaxf(mx, __shfl_xor(mx, off));
    if (lane == 0) red[w] = mx;
    __syncthreads();
    mx = fmaxf(fmaxf(red[0], red[1]), fmaxf(red[2], red[3]));
    __syncthreads();

    float s = 0.f;
#pragma unroll
    for (int i = 0; i < 8; ++i) { v[i] = __expf(v[i] - mx); s += v[i]; }
#pragma unroll
    for (int off = 32; off; off >>= 1) s += __shfl_xor(s, off);
    if (lane == 0) red[w] = s;
    __syncthreads();
    s = (red[0] + red[1]) + (red[2] + red[3]);
    const float inv = 1.0f / s;

    unsigned short* o = W + row * (size_t)N;
#pragma unroll
    for (int i = 0; i < 8; ++i) o[t + (i << 8)] = f2bf(v[i] * inv);
}

// ---------------------------------------------------------------------------
// K2: bell (bf16 GEMM A operand) + per-row spikes stats (ss, sss) fused.
//     Requires N % 256 == 0 so each wave's 64 consecutive float4 stay in
//     one row (row4 = N/4 divisible by 64).
// ---------------------------------------------------------------------------
__global__ void __launch_bounds__(256) bell_stats_k(const float* __restrict__ spikes,
                                                    const float* __restrict__ Wbell,
                                                    unsigned short* __restrict__ bellb,
                                                    float* __restrict__ RS,   // [M][2]
                                                    int N, size_t total4) {
    const size_t stride = (size_t)gridDim.x * blockDim.x;
    const unsigned int row4 = (unsigned int)(N >> 2);
    const int lane = threadIdx.x & 63;
    for (size_t i = (size_t)blockIdx.x * blockDim.x + threadIdx.x; i < total4; i += stride) {
        const float4 x = reinterpret_cast<const float4*>(spikes)[i];
        const unsigned int ii = (unsigned int)i;
        const unsigned int row = ii / row4;           // wave-uniform
        const int c4 = (int)((ii - row * row4) << 2); // column of first element
        const int p = c4 >> 1;                        // first pair index
        const float4 w0 = reinterpret_cast<const float4*>(Wbell)[p];
        const float4 w1 = reinterpret_cast<const float4*>(Wbell)[p + 1];
        float4 y;
        y.x = w0.x * x.x + w0.y * x.y;
        y.y = w0.z * x.x + w0.w * x.y;
        y.z = w1.x * x.z + w1.y * x.w;
        y.w = w1.z * x.z + w1.w * x.w;
        ushort4 h;
        h.x = f2bf(y.x); h.y = f2bf(y.y); h.z = f2bf(y.z); h.w = f2bf(y.w);
        reinterpret_cast<ushort4*>(bellb)[i] = h;

        float ss = (x.x + x.y) + (x.z + x.w);
        float sss = (x.x * x.x + x.y * x.y) + (x.z * x.z + x.w * x.w);
#pragma unroll
        for (int off = 32; off; off >>= 1) {
            ss += __shfl_xor(ss, off);
            sss += __shfl_xor(sss, off);
        }
        if (lane == 0) {
            atomicAdd(&RS[(size_t)row * 2 + 0], ss);
            atomicAdd(&RS[(size_t)row * 2 + 1], sss);
        }
    }
}

// ---------------------------------------------------------------------------
// K3: C[m,n] = sum_k bell[m,k] * W[n,k]  (bf16 MFMA, 128x128 tile, BK=32,
//     4 waves 2x2, global_load_lds width 16, 2-phase double-buffered LDS:
//     stage(t+1) issued BEFORE compute(t), ONE barrier per K-step).
//     Epilogue: out = clip(0.5*bell + 0.5*C, 0, 1) with bell recomputed in
//     f32 from spikes (L3-resident), fused entangled row-stats (se,see,sse).
// ---------------------------------------------------------------------------
__global__ void __launch_bounds__(256) gemm_entangle_k(
    const unsigned short* __restrict__ A,   // bell bf16 [M][K]
    const unsigned short* __restrict__ Bt,  // W bf16 [N][K]
    const float* __restrict__ spikes,       // [M][K]
    const float* __restrict__ Wbell,        // [K/2][2][2]
    float* __restrict__ out,                // entangled [M][N]
    float* __restrict__ RE,                 // [M][4] se,see,sse,pad
    int M, int N, int K) {
    __shared__ unsigned short As[2][128 * 32];
    __shared__ unsigned short Bs[2][128 * 32];

    const int tid = threadIdx.x;
    const int lane = tid & 63;
    const int wave = tid >> 6;
    const int wr = wave >> 1;   // 2x2 waves, each 64x64 subtile
    const int wc = wave & 1;

    // XCD-aware bijective swizzle (grid is a multiple of 8)
    const int nwg = gridDim.x;
    const int bid = blockIdx.x;
    int wg;
    if ((nwg & 7) == 0) {
        const int cpx = nwg >> 3;
        wg = (bid & 7) * cpx + (bid >> 3);
    } else {
        wg = bid;
    }
    const int ntn = N >> 7;
    const int tm = wg / ntn;
    const int tn = wg - tm * ntn;
    const size_t m0 = (size_t)tm << 7;
    const size_t n0 = (size_t)tn << 7;

    // staging: each thread covers 16B = 8 bf16; row tid/4, 16B-chunk tid%4
    const int r_a = tid >> 2;
    const int cb = (tid & 3) << 3;

    f32x4 acc[4][4];
#pragma unroll
    for (int i = 0; i < 4; ++i)
#pragma unroll
        for (int j = 0; j < 4; ++j) acc[i][j] = (f32x4)(0.f);

    const unsigned short* ga0 = A + (m0 + r_a) * (size_t)K + cb;
    const unsigned short* ga1 = A + (m0 + 64 + r_a) * (size_t)K + cb;
    const unsigned short* gb0 = Bt + (n0 + r_a) * (size_t)K + cb;
    const unsigned short* gb1 = Bt + (n0 + 64 + r_a) * (size_t)K + cb;

    const int rsel = lane & 15;
    const int ksel = (lane >> 4) << 3;

#define STAGE(sel, k0)                                                                                        \
    do {                                                                                                      \
        unsigned short* lA = &As[sel][wave * 512];                                                            \
        unsigned short* lB = &Bs[sel][wave * 512];                                                            \
        __builtin_amdgcn_global_load_lds((const __attribute__((address_space(1))) void*)(ga0 + (k0)),         \
                                         (__attribute__((address_space(3))) void*)(lA), 16, 0, 0);            \
        __builtin_amdgcn_global_load_lds((const __attribute__((address_space(1))) void*)(ga1 + (k0)),         \
                                         (__attribute__((address_space(3))) void*)(lA + 2048), 16, 0, 0);     \
        __builtin_amdgcn_global_load_lds((const __attribute__((address_space(1))) void*)(gb0 + (k0)),         \
                                         (__attribute__((address_space(3))) void*)(lB), 16, 0, 0);            \
        __builtin_amdgcn_global_load_lds((const __attribute__((address_space(1))) void*)(gb1 + (k0)),         \
                                         (__attribute__((address_space(3))) void*)(lB + 2048), 16, 0, 0);     \
    } while (0)

    const int NT = K >> 5;
    STAGE(0, 0);
    __syncthreads();   // compiler drains vmcnt(0) before s_barrier
    int cur = 0;
    for (int t = 0; t < NT; ++t) {
        if (t + 1 < NT) STAGE(cur ^ 1, (t + 1) << 5);   // loads fly during compute(t)
        bf16x8 af[4], bfr[4];
#pragma unroll
        for (int i = 0; i < 4; ++i) {
            af[i] = *reinterpret_cast<const bf16x8*>(&As[cur][(wr * 64 + i * 16 + rsel) * 32 + ksel]);
            bfr[i] = *reinterpret_cast<const bf16x8*>(&Bs[cur][(wc * 64 + i * 16 + rsel) * 32 + ksel]);
        }
#pragma unroll
        for (int i = 0; i < 4; ++i)
#pragma unroll
            for (int j = 0; j < 4; ++j)
                acc[i][j] = __builtin_amdgcn_mfma_f32_16x16x32_bf16(af[i], bfr[j], acc[i][j], 0, 0, 0);
        __syncthreads();   // drains staged loads of t+1; protects buffer reuse
        cur ^= 1;
    }
#undef STAGE

    // ---- epilogue: bell recompute (f32), entangle, clip, store, row stats ----
    float wa[4], wb[4];
    int p2[4], par[4];
#pragma unroll
    for (int j = 0; j < 4; ++j) {
        const int col = (int)n0 + wc * 64 + j * 16 + rsel;
        p2[j] = col & ~1;
        par[j] = col & 1;
        const float* wp = Wbell + ((size_t)(col >> 1) << 2) + ((size_t)(col & 1) << 1);
        wa[j] = wp[0];
        wb[j] = wp[1];
    }
    const int g = lane >> 4;
#pragma unroll
    for (int i = 0; i < 4; ++i) {
#pragma unroll
        for (int r = 0; r < 4; ++r) {
            const size_t row = m0 + wr * 64 + i * 16 + g * 4 + r;
            const float* srow = spikes + row * (size_t)K;
            float se = 0.f, see = 0.f, sse = 0.f;
#pragma unroll
            for (int j = 0; j < 4; ++j) {
                const float s0v = srow[p2[j]];
                const float s1v = srow[p2[j] + 1];
                const float bv = wa[j] * s0v + wb[j] * s1v;
                float ev = 0.5f * bv + 0.5f * acc[i][j][r];
                ev = fminf(fmaxf(ev, 0.f), 1.f);
                const int col = (int)n0 + wc * 64 + j * 16 + rsel;
                out[row * (size_t)N + col] = ev;
                const float sv = par[j] ? s1v : s0v;
                se += ev;
                see += ev * ev;
                sse += sv * ev;
            }
            // reduce across the 16-lane group (same g), then one atomic set
#pragma unroll
            for (int off = 1; off < 16; off <<= 1) {
                se += __shfl_xor(se, off);
                see += __shfl_xor(see, off);
                sse += __shfl_xor(sse, off);
            }
            if (rsel == 0) {
                atomicAdd(&RE[row * 4 + 0], se);
                atomicAdd(&RE[row * 4 + 1], see);
                atomicAdd(&RE[row * 4 + 2], sse);
            }
        }
    }
}

// ---------------------------------------------------------------------------
// K4: finisher — per-row cosine similarity from the 5 stats, mean(|.|).
// ---------------------------------------------------------------------------
__global__ void __launch_bounds__(256) corr_final_k(const float* __restrict__ RS,
                                                    const float* __restrict__ RE,
                                                    float* __restrict__ corr_out,
                                                    int Brows, int N, float scale) {
    __shared__ float red[4];
    const int lane = threadIdx.x & 63;
    const int w = threadIdx.x >> 6;
    float local = 0.f;
    for (int r = blockIdx.x * blockDim.x + threadIdx.x; r < Brows;
         r += gridDim.x * blockDim.x) {
        const float ss = RS[(size_t)r * 2 + 0];
        const float sss = RS[(size_t)r * 2 + 1];
        const float se = RE[(size_t)r * 4 + 0];
        const float see = RE[(size_t)r * 4 + 1];
        const float sse = RE[(size_t)r * 4 + 2];
        const float n = (float)N;
        const float dot = sse - ss * se / n;
        const float na = fmaxf(sqrtf(fmaxf(sss - ss * ss / n, 0.f)), 1e-8f);
        const float nb = fmaxf(sqrtf(fmaxf(see - se * se / n, 0.f)), 1e-8f);
        local += fabsf(dot / (na * nb));
    }
#pragma unroll
    for (int off = 32; off; off >>= 1) local += __shfl_xor(local, off);
    if (lane == 0) red[w] = local;
    __syncthreads();
    if (threadIdx.x == 0)
        atomicAdd(corr_out, ((red[0] + red[1]) + (red[2] + red[3])) * scale);
}

// ---------------------------------------------------------------------------
extern "C" void kernel_launch(void* const* d_in, const int* in_sizes, int n_in,
                              void* d_out, int out_size, void* d_ws, size_t ws_size,
                              hipStream_t stream) {
    const float* spikes = (const float*)d_in[0];
    const float* Wbell = (const float*)d_in[1];
    const float* E = (const float*)d_in[2];
    float* outf = (float*)d_out;

    const int N = (int)(sqrt((double)in_sizes[2]) + 0.5);
    const int Brows = in_sizes[0] / N;

    // workspace: W_bf16 [N*N] | bell_bf16 [B*N] | RS [B*2] f32 | RE [B*4] f32
    unsigned short* Wb = (unsigned short*)d_ws;
    unsigned short* bellb = Wb + (size_t)N * N;
    float* RS = (float*)(bellb + (size_t)Brows * N);
    float* RE = RS + (size_t)Brows * 2;

    // zero the stats area (RS+RE contiguous) and the corr accumulator
    hipMemsetAsync(RS, 0, (size_t)Brows * 6 * sizeof(float), stream);
    hipMemsetAsync(outf + (size_t)Brows * N, 0, sizeof(float), stream);

    softmax_rows_k<<<N, 256, 0, stream>>>(E, Wb, N);

    const size_t total4 = ((size_t)Brows * N) >> 2;
    bell_stats_k<<<4096, 256, 0, stream>>>(spikes, Wbell, bellb, RS, N, total4);

    const int nblocks = (Brows >> 7) * (N >> 7);
    gemm_entangle_k<<<nblocks, 256, 0, stream>>>(bellb, Wb, spikes, Wbell,
                                                 outf, RE, Brows, N, N);

    corr_final_k<<<64, 256, 0, stream>>>(RS, RE, outf + (size_t)Brows * N,
                                         Brows, N, 1.0f / (float)Brows);
}

// Round 13
// 441.373 us; speedup vs baseline: 1.5472x; 1.5472x over previous
//
#include <hip/hip_runtime.h>
#include <hip/hip_bf16.h>
#include <math.h>

typedef __attribute__((ext_vector_type(8))) __bf16 bf16x8;
typedef __attribute__((ext_vector_type(4))) float f32x4;

static __device__ __forceinline__ unsigned short f2bf(float f) {
    unsigned int u = __float_as_uint(f);
    u += 0x7fffu + ((u >> 16) & 1u);   // round-to-nearest-even
    return (unsigned short)(u >> 16);
}

// ---------------------------------------------------------------------------
// K1: Bt'[n][k] = bf16( 0.5*softmax(E[n,:])[k] + 0.5*(k==n) ).
//     Folding the residual (1-MIX)*bell into the GEMM's B matrix makes the
//     GEMM output the full pre-clip entangled value -> d_out becomes
//     single-writer/write-once (fixes R12's post-timing divergence).
// ---------------------------------------------------------------------------
__global__ void __launch_bounds__(256) softmax_fold_k(const float* __restrict__ E,
                                                      unsigned short* __restrict__ W,
                                                      int N) {
    __shared__ float red[4];
    const int t = threadIdx.x;
    const int lane = t & 63;
    const int w = t >> 6;
    const size_t row = blockIdx.x;
    const float* e = E + row * (size_t)N;

    float v[8];
    float mx = -3.402823466e38f;
#pragma unroll
    for (int i = 0; i < 8; ++i) { v[i] = e[t + (i << 8)]; mx = fmaxf(mx, v[i]); }
#pragma unroll
    for (int off = 32; off; off >>= 1) mx = fmaxf(mx, __shfl_xor(mx, off));
    if (lane == 0) red[w] = mx;
    __syncthreads();
    mx = fmaxf(fmaxf(red[0], red[1]), fmaxf(red[2], red[3]));
    __syncthreads();

    float s = 0.f;
#pragma unroll
    for (int i = 0; i < 8; ++i) { v[i] = __expf(v[i] - mx); s += v[i]; }
#pragma unroll
    for (int off = 32; off; off >>= 1) s += __shfl_xor(s, off);
    if (lane == 0) red[w] = s;
    __syncthreads();
    s = (red[0] + red[1]) + (red[2] + red[3]);
    const float half_inv = 0.5f / s;

    unsigned short* o = W + row * (size_t)N;
#pragma unroll
    for (int i = 0; i < 8; ++i) {
        const int col = t + (i << 8);
        float val = v[i] * half_inv;           // 0.5 * softmax
        if (col == (int)row) val += 0.5f;      // + 0.5 * I  (residual fold)
        o[col] = f2bf(val);
    }
}

// ---------------------------------------------------------------------------
// K2: bell = block-diagonal 2x2 linear -> bf16 GEMM A operand.
// ---------------------------------------------------------------------------
__global__ void __launch_bounds__(256) bell_k(const float* __restrict__ spikes,
                                              const float* __restrict__ Wbell,
                                              unsigned short* __restrict__ bellb,
                                              int N, size_t total4) {
    const size_t stride = (size_t)gridDim.x * blockDim.x;
    const unsigned int row4 = (unsigned int)(N >> 2);
    for (size_t i = (size_t)blockIdx.x * blockDim.x + threadIdx.x; i < total4; i += stride) {
        const float4 x = reinterpret_cast<const float4*>(spikes)[i];
        const unsigned int ii = (unsigned int)i;
        const unsigned int row = ii / row4;
        const int c4 = (int)((ii - row * row4) << 2);
        const int p = c4 >> 1;
        const float4 w0 = reinterpret_cast<const float4*>(Wbell)[p];
        const float4 w1 = reinterpret_cast<const float4*>(Wbell)[p + 1];
        float4 y;
        y.x = w0.x * x.x + w0.y * x.y;
        y.y = w0.z * x.x + w0.w * x.y;
        y.z = w1.x * x.z + w1.y * x.w;
        y.w = w1.z * x.z + w1.w * x.w;
        ushort4 h;
        h.x = f2bf(y.x); h.y = f2bf(y.y); h.z = f2bf(y.z); h.w = f2bf(y.w);
        reinterpret_cast<ushort4*>(bellb)[i] = h;
    }
}

// ---------------------------------------------------------------------------
// K3: entangled[m,n] = clip( sum_k bell[m,k] * Bt'[n,k], 0, 1 )
//     (bf16 MFMA, 128x128 tile, BK=32, 4 waves 2x2, global_load_lds w=16,
//      2-phase double-buffered LDS, ONE barrier per K-step.)
//     out is written exactly ONCE by this kernel -> byte-identical across
//     graph replays; no cross-kernel RMW of d_out anywhere.
// ---------------------------------------------------------------------------
__global__ void __launch_bounds__(256) gemm_k(
    const unsigned short* __restrict__ A,   // bell bf16 [M][K]
    const unsigned short* __restrict__ Bt,  // W' bf16 [N][K]
    float* __restrict__ out,                // entangled [M][N]
    int M, int N, int K) {
    __shared__ unsigned short As[2][128 * 32];
    __shared__ unsigned short Bs[2][128 * 32];

    const int tid = threadIdx.x;
    const int lane = tid & 63;
    const int wave = tid >> 6;
    const int wr = wave >> 1;
    const int wc = wave & 1;

    // XCD-aware bijective swizzle (grid is a multiple of 8)
    const int nwg = gridDim.x;
    const int bid = blockIdx.x;
    int wg;
    if ((nwg & 7) == 0) {
        const int cpx = nwg >> 3;
        wg = (bid & 7) * cpx + (bid >> 3);
    } else {
        wg = bid;
    }
    const int ntn = N >> 7;
    const int tm = wg / ntn;
    const int tn = wg - tm * ntn;
    const size_t m0 = (size_t)tm << 7;
    const size_t n0 = (size_t)tn << 7;

    const int r_a = tid >> 2;
    const int cb = (tid & 3) << 3;

    f32x4 acc[4][4];
#pragma unroll
    for (int i = 0; i < 4; ++i)
#pragma unroll
        for (int j = 0; j < 4; ++j) acc[i][j] = (f32x4)(0.f);

    const unsigned short* ga0 = A + (m0 + r_a) * (size_t)K + cb;
    const unsigned short* ga1 = A + (m0 + 64 + r_a) * (size_t)K + cb;
    const unsigned short* gb0 = Bt + (n0 + r_a) * (size_t)K + cb;
    const unsigned short* gb1 = Bt + (n0 + 64 + r_a) * (size_t)K + cb;

    const int rsel = lane & 15;
    const int ksel = (lane >> 4) << 3;

#define STAGE(sel, k0)                                                                                        \
    do {                                                                                                      \
        unsigned short* lA = &As[sel][wave * 512];                                                            \
        unsigned short* lB = &Bs[sel][wave * 512];                                                            \
        __builtin_amdgcn_global_load_lds((const __attribute__((address_space(1))) void*)(ga0 + (k0)),         \
                                         (__attribute__((address_space(3))) void*)(lA), 16, 0, 0);            \
        __builtin_amdgcn_global_load_lds((const __attribute__((address_space(1))) void*)(ga1 + (k0)),         \
                                         (__attribute__((address_space(3))) void*)(lA + 2048), 16, 0, 0);     \
        __builtin_amdgcn_global_load_lds((const __attribute__((address_space(1))) void*)(gb0 + (k0)),         \
                                         (__attribute__((address_space(3))) void*)(lB), 16, 0, 0);            \
        __builtin_amdgcn_global_load_lds((const __attribute__((address_space(1))) void*)(gb1 + (k0)),         \
                                         (__attribute__((address_space(3))) void*)(lB + 2048), 16, 0, 0);     \
    } while (0)

    const int NT = K >> 5;
    STAGE(0, 0);
    __syncthreads();
    int cur = 0;
    for (int t = 0; t < NT; ++t) {
        if (t + 1 < NT) STAGE(cur ^ 1, (t + 1) << 5);
        bf16x8 af[4], bfr[4];
#pragma unroll
        for (int i = 0; i < 4; ++i) {
            af[i] = *reinterpret_cast<const bf16x8*>(&As[cur][(wr * 64 + i * 16 + rsel) * 32 + ksel]);
            bfr[i] = *reinterpret_cast<const bf16x8*>(&Bs[cur][(wc * 64 + i * 16 + rsel) * 32 + ksel]);
        }
#pragma unroll
        for (int i = 0; i < 4; ++i)
#pragma unroll
            for (int j = 0; j < 4; ++j)
                acc[i][j] = __builtin_amdgcn_mfma_f32_16x16x32_bf16(af[i], bfr[j], acc[i][j], 0, 0, 0);
        __syncthreads();
        cur ^= 1;
    }
#undef STAGE

    // epilogue: clip + coalesced store (single writer of out)
    const int g = lane >> 4;
#pragma unroll
    for (int i = 0; i < 4; ++i) {
#pragma unroll
        for (int j = 0; j < 4; ++j) {
            const int col = (int)n0 + wc * 64 + j * 16 + rsel;
#pragma unroll
            for (int r = 0; r < 4; ++r) {
                const size_t row = m0 + wr * 64 + i * 16 + g * 4 + r;
                out[row * (size_t)N + col] = fminf(fmaxf(acc[i][j][r], 0.f), 1.f);
            }
        }
    }
}

// ---------------------------------------------------------------------------
// K4: cosine-similarity corr — PURE READER of spikes + entangled (R2's
//     proven-passing structure).  4 waves/block, rows strided; one atomic
//     per block.
// ---------------------------------------------------------------------------
__global__ void __launch_bounds__(256) corr_k(const float* __restrict__ spikes,
                                              const float* __restrict__ ent,
                                              float* __restrict__ corr_out,
                                              int Brows, int N, float scale) {
    __shared__ float wsum[4];
    const int lane = threadIdx.x & 63;
    const int w = threadIdx.x >> 6;
    const int n4 = N >> 2;
    float local = 0.f;

    for (int row = blockIdx.x * 4 + w; row < Brows; row += gridDim.x * 4) {
        const float4* s = reinterpret_cast<const float4*>(spikes + (size_t)row * N);
        const float4* e = reinterpret_cast<const float4*>(ent + (size_t)row * N);
        float ss = 0.f, se = 0.f, sss = 0.f, see = 0.f, sse = 0.f;
        for (int i = lane; i < n4; i += 64) {
            const float4 a = s[i];
            const float4 b = e[i];
            ss += (a.x + a.y) + (a.z + a.w);
            se += (b.x + b.y) + (b.z + b.w);
            sss += (a.x * a.x + a.y * a.y) + (a.z * a.z + a.w * a.w);
            see += (b.x * b.x + b.y * b.y) + (b.z * b.z + b.w * b.w);
            sse += (a.x * b.x + a.y * b.y) + (a.z * b.z + a.w * b.w);
        }
#pragma unroll
        for (int off = 32; off; off >>= 1) {
            ss += __shfl_xor(ss, off);
            se += __shfl_xor(se, off);
            sss += __shfl_xor(sss, off);
            see += __shfl_xor(see, off);
            sse += __shfl_xor(sse, off);
        }
        if (lane == 0) {
            const float n = (float)N;
            const float dot = sse - ss * se / n;
            const float na = fmaxf(sqrtf(fmaxf(sss - ss * ss / n, 0.f)), 1e-8f);
            const float nb = fmaxf(sqrtf(fmaxf(see - se * se / n, 0.f)), 1e-8f);
            local += fabsf(dot / (na * nb));
        }
    }
    if (lane == 0) wsum[w] = local;
    __syncthreads();
    if (threadIdx.x == 0)
        atomicAdd(corr_out, ((wsum[0] + wsum[1]) + (wsum[2] + wsum[3])) * scale);
}

// ---------------------------------------------------------------------------
extern "C" void kernel_launch(void* const* d_in, const int* in_sizes, int n_in,
                              void* d_out, int out_size, void* d_ws, size_t ws_size,
                              hipStream_t stream) {
    const float* spikes = (const float*)d_in[0];
    const float* Wbell = (const float*)d_in[1];
    const float* E = (const float*)d_in[2];
    float* outf = (float*)d_out;

    const int N = (int)(sqrt((double)in_sizes[2]) + 0.5);
    const int Brows = in_sizes[0] / N;

    // workspace: W' bf16 [N*N] | bell bf16 [B*N]
    unsigned short* Wb = (unsigned short*)d_ws;
    unsigned short* bellb = Wb + (size_t)N * N;

    // zero the bell_corr accumulator slot (d_out is poisoned each launch)
    hipMemsetAsync(outf + (size_t)Brows * N, 0, sizeof(float), stream);

    softmax_fold_k<<<N, 256, 0, stream>>>(E, Wb, N);

    const size_t total4 = ((size_t)Brows * N) >> 2;
    bell_k<<<4096, 256, 0, stream>>>(spikes, Wbell, bellb, N, total4);

    const int nblocks = (Brows >> 7) * (N >> 7);
    gemm_k<<<nblocks, 256, 0, stream>>>(bellb, Wb, outf, Brows, N, N);

    corr_k<<<1024, 256, 0, stream>>>(spikes, outf, outf + (size_t)Brows * N,
                                     Brows, N, 1.0f / (float)Brows);
}